// Round 1
// baseline (377.145 us; speedup 1.0000x reference)
//
#include <hip/hip_runtime.h>

// Problem constants
#define T_STEPS 8
#define NROW    42            // C*Dp = 3*14
#define BN      2688          // B*NROW = 64*42
#define H0      256
#define H1      128
#define NCLS    6
#define KFLAT   5376          // NROW*H1

// ---------------------------------------------------------------------------
// K1: avg-pool3d (2,2,2)/(2,2,2) VALID over (D=29,H=32,W=32) chunks.
// Output pr[m][f], m = t*2688 + b*42 + c*14 + dp, f = hp*16 + wp.
// ---------------------------------------------------------------------------
__global__ __launch_bounds__(256) void pool_kernel(const float* __restrict__ x,
                                                   float* __restrict__ pr) {
    int idx = blockIdx.x * 256 + threadIdx.x;      // < 5,505,024
    int f   = idx & 255;
    int wp  = f & 15, hp = f >> 4;
    int rest = idx >> 8;                           // (t,b,c,dp), 21504 total
    int dp = rest % 14;
    int r2 = rest / 14;
    int c  = r2 % 3;
    int r3 = r2 / 3;
    int b  = r3 & 63;
    int t  = r3 >> 6;
    // x strides: w=1, h=32, d=1024, c=237568, b=712704
    const float* base = x + ((long)b * 712704 + (long)c * 237568
                          + (long)(t * 29 + 2 * dp) * 1024
                          + (2 * hp) * 32 + 2 * wp);
    float2 v0 = *(const float2*)(base);
    float2 v1 = *(const float2*)(base + 32);
    float2 v2 = *(const float2*)(base + 1024);
    float2 v3 = *(const float2*)(base + 1056);
    float s = v0.x + v0.y + v1.x + v1.y + v2.x + v2.y + v3.x + v3.y;
    int m = t * BN + b * NROW + c * 14 + dp;
    pr[(long)m * 256 + f] = s * 0.125f;
}

// ---------------------------------------------------------------------------
// K2/K4: C[M x N] = A[M x K] * B[N x K]^T + bias.  64x64 tile, 4x4/thread.
// LDS tiles stored transposed [k][row], pad 68 (16B-aligned b128, conflict-free).
// ---------------------------------------------------------------------------
__global__ __launch_bounds__(256) void gemm_abt(const float* __restrict__ A,
                                                const float* __restrict__ B,
                                                const float* __restrict__ bias,
                                                float* __restrict__ C,
                                                int N, int K) {
    __shared__ float At[16][68];
    __shared__ float Bt[16][68];
    int tid = threadIdx.x;
    int m0 = blockIdx.y * 64, n0 = blockIdx.x * 64;
    int lr = tid >> 2;        // 0..63 tile row for staging
    int lq = tid & 3;         // float4 slot along k
    int tm = tid & 15, tn = tid >> 4;
    float acc[4][4] = {};
    const float* Ap = A + (long)(m0 + lr) * K + lq * 4;
    const float* Bp = B + (long)(n0 + lr) * K + lq * 4;
    for (int k0 = 0; k0 < K; k0 += 16) {
        float4 a = *(const float4*)(Ap + k0);
        float4 b = *(const float4*)(Bp + k0);
        __syncthreads();
        At[lq * 4 + 0][lr] = a.x; At[lq * 4 + 1][lr] = a.y;
        At[lq * 4 + 2][lr] = a.z; At[lq * 4 + 3][lr] = a.w;
        Bt[lq * 4 + 0][lr] = b.x; Bt[lq * 4 + 1][lr] = b.y;
        Bt[lq * 4 + 2][lr] = b.z; Bt[lq * 4 + 3][lr] = b.w;
        __syncthreads();
#pragma unroll
        for (int k = 0; k < 16; ++k) {
            float4 av = *(const float4*)&At[k][tm * 4];
            float4 bv = *(const float4*)&Bt[k][tn * 4];
            float am[4] = {av.x, av.y, av.z, av.w};
            float bn_[4] = {bv.x, bv.y, bv.z, bv.w};
#pragma unroll
            for (int i = 0; i < 4; ++i)
#pragma unroll
                for (int j = 0; j < 4; ++j)
                    acc[i][j] = fmaf(am[i], bn_[j], acc[i][j]);
        }
    }
#pragma unroll
    for (int i = 0; i < 4; ++i) {
        int row = m0 + tm * 4 + i;
        int col = n0 + tn * 4;
        float4 o;
        o.x = acc[i][0] + bias[col + 0];
        o.y = acc[i][1] + bias[col + 1];
        o.z = acc[i][2] + bias[col + 2];
        o.w = acc[i][3] + bias[col + 3];
        *(float4*)&C[(long)row * N + col] = o;
    }
}

// ---------------------------------------------------------------------------
// K3/K5: LIF recurrence over t (per-scalar independent). F in {256,128}.
// reset from PREVIOUS mem (strict >), reset-by-subtract, spike = (mem-thr)>0.
// ---------------------------------------------------------------------------
__global__ __launch_bounds__(256) void lif_kernel(const float* __restrict__ cur_all,
                                                  const float* __restrict__ beta,
                                                  const float* __restrict__ thr,
                                                  float* __restrict__ spk_all,
                                                  int F) {
    int j = blockIdx.x * 256 + threadIdx.x;   // < BN*F
    int h = j & (F - 1);
    float be = fminf(fmaxf(beta[h], 0.f), 1.f);
    float th = thr[h];
    float mem = 0.f;
    long stride = (long)BN * F;
#pragma unroll
    for (int t = 0; t < T_STEPS; ++t) {
        float cur = cur_all[t * stride + j];
        float reset = (mem > th) ? th : 0.f;
        mem = be * mem + cur - reset;
        spk_all[t * stride + j] = ((mem - th) > 0.f) ? 1.f : 0.f;
    }
}

// ---------------------------------------------------------------------------
// K6: cur_out[row=(t*64+b)][cls] = sum_f spkh[row][f]*W_out[cls][f] + b_out
// ---------------------------------------------------------------------------
__global__ __launch_bounds__(256) void out_gemm(const float* __restrict__ spkh,
                                                const float* __restrict__ W_out,
                                                const float* __restrict__ b_out,
                                                float* __restrict__ cur_out) {
    __shared__ float part[256][8];
    int row = blockIdx.x;                    // t*64 + b
    int tid = threadIdx.x;
    const float* a = spkh + (long)row * KFLAT;
    float acc[6] = {0.f, 0.f, 0.f, 0.f, 0.f, 0.f};
    for (int j = tid; j < KFLAT; j += 256) {
        float s = a[j];
#pragma unroll
        for (int c = 0; c < 6; ++c)
            acc[c] = fmaf(s, W_out[c * KFLAT + j], acc[c]);
    }
#pragma unroll
    for (int c = 0; c < 6; ++c) part[tid][c] = acc[c];
    __syncthreads();
    for (int off = 128; off > 0; off >>= 1) {
        if (tid < off) {
#pragma unroll
            for (int c = 0; c < 6; ++c) part[tid][c] += part[tid + off][c];
        }
        __syncthreads();
    }
    if (tid < 6) cur_out[row * 6 + tid] = part[0][tid] + b_out[tid];
}

// ---------------------------------------------------------------------------
// K7: output-layer LIF (threshold 1.0), writes spikes (8,64,6) to d_out
// ---------------------------------------------------------------------------
__global__ void lif_out_kernel(const float* __restrict__ cur_out,
                               const float* __restrict__ beta_out,
                               float* __restrict__ out) {
    int j = threadIdx.x;                     // < 384, j = b*6 + cls
    if (j >= 384) return;
    int cls = j % 6;
    float be = fminf(fmaxf(beta_out[cls], 0.f), 1.f);
    float mem = 0.f;
#pragma unroll
    for (int t = 0; t < T_STEPS; ++t) {
        float cur = cur_out[t * 384 + j];
        float reset = (mem > 1.f) ? 1.f : 0.f;
        mem = be * mem + cur - reset;
        out[t * 384 + j] = ((mem - 1.f) > 0.f) ? 1.f : 0.f;
    }
}

extern "C" void kernel_launch(void* const* d_in, const int* in_sizes, int n_in,
                              void* d_out, int out_size, void* d_ws, size_t ws_size,
                              hipStream_t stream) {
    (void)in_sizes; (void)n_in; (void)out_size; (void)ws_size;
    const float* x        = (const float*)d_in[0];
    const float* W_in     = (const float*)d_in[1];
    const float* b_in     = (const float*)d_in[2];
    const float* W_hid    = (const float*)d_in[3];
    const float* b_hid    = (const float*)d_in[4];
    const float* W_out    = (const float*)d_in[5];
    const float* b_out    = (const float*)d_in[6];
    const float* beta_in  = (const float*)d_in[7];
    const float* thr_in   = (const float*)d_in[8];
    const float* beta_hid = (const float*)d_in[9];
    const float* thr_hid  = (const float*)d_in[10];
    const float* beta_out = (const float*)d_in[11];
    float* out = (float*)d_out;

    // workspace: two 22MB ping-pong buffers + tiny cur_out (total ~44 MB)
    float* buf0 = (float*)d_ws;            // 5,505,024 floats
    float* buf1 = buf0 + 5505024;          // 5,505,024 floats
    float* curo = buf1 + 5505024;          // 3,072 floats

    // 1. pool: x -> pr (buf0)
    pool_kernel<<<21504, 256, 0, stream>>>(x, buf0);
    // 2. cur_in_all = pr @ W_in^T + b_in  (buf0 -> buf1), M=21504,N=256,K=256
    gemm_abt<<<dim3(4, 336), 256, 0, stream>>>(buf0, W_in, b_in, buf1, 256, 256);
    // 3. LIF_in: buf1 -> spk_in_all (buf0)
    lif_kernel<<<2688, 256, 0, stream>>>(buf1, beta_in, thr_in, buf0, 256);
    // 4. cur_hid_all = spk_in @ W_hid^T + b_hid (buf0 -> buf1), N=128
    gemm_abt<<<dim3(2, 336), 256, 0, stream>>>(buf0, W_hid, b_hid, buf1, 128, 256);
    // 5. LIF_hid: buf1 -> spk_hid_all (buf0)
    lif_kernel<<<1344, 256, 0, stream>>>(buf1, beta_hid, thr_hid, buf0, 128);
    // 6. cur_out_all: (t,b) rows x 5376 -> 6
    out_gemm<<<512, 256, 0, stream>>>(buf0, W_out, b_out, curo);
    // 7. output LIF -> d_out
    lif_out_kernel<<<1, 384, 0, stream>>>(curo, beta_out, out);
}